// Round 9
// baseline (99.024 us; speedup 1.0000x reference)
//
#include <hip/hip_runtime.h>
#include <math.h>

#define BB 32
#define CC 5
#define HH 50
#define LL 32
#define LEV 3
#define DD 256
#define KK 10
#define THRESH 0.1f
#define EPSF 1e-12f
#define RPB 8                      // rows per block in proj kernel
#define NPROJ ((BB * CC + BB * HH) / RPB)   // 220 blocks
#define INNER (LL * LEV * DD)      // 24576 floats per (b,c,k)
#define INNER4 (INNER / 4)         // 6144 float4 per (b,c,k)
#define NBCK (BB * CC * KK)        // 1600 output rows
#define TOTAL4 (NBCK * INNER4)     // 9,830,400 float4 total
#define CHUNKS 4
#define PERCH (INNER4 / CHUNKS)    // 1536 float4 per chunk (6 per thread @256)
#define NFILL 2048                 // fill grid: 8 blocks/CU, clone of driver fill shape

typedef float f32x4 __attribute__((ext_vector_type(4)));

// ---------------- Kernel 0: pure linear zero-fill of d_out, driver-fill clone.
// No LDS, no branches, no table: maximally similar to fillBufferAligned (7 TB/s).
__global__ __launch_bounds__(256)
void zero_fill_kernel(float* __restrict__ out)
{
    f32x4* __restrict__ dst4 = (f32x4*)out;
    const f32x4 z = (f32x4){0.f, 0.f, 0.f, 0.f};
    const unsigned stride = NFILL * 256;
    for (unsigned i = blockIdx.x * 256 + threadIdx.x; i < TOTAL4; i += stride)
        dst4[i] = z;                 // normal stores: the proven 7 TB/s shape
}

// ---------------- Kernel 1: y = l2norm(x @ W + b), 8 rows per block.
__global__ void proj_norm_kernel(const float* __restrict__ cdd,
                                 const float* __restrict__ his,
                                 const float* __restrict__ W,
                                 const float* __restrict__ bias,
                                 float* __restrict__ c_out,   // [B*C, D]
                                 float* __restrict__ h_out)   // [B*H, D]
{
    const int row0 = blockIdx.x * RPB;
    const int j    = threadIdx.x;     // 0..255
    const int wid  = j >> 6;
    const int lane = j & 63;

    __shared__ float xs[RPB][DD];
    #pragma unroll
    for (int r = 0; r < RPB; ++r) {
        const int row = row0 + r;
        const float* x = (row < BB * CC) ? (cdd + (size_t)row * DD)
                                         : (his + (size_t)(row - BB * CC) * DD);
        xs[r][j] = x[j];
    }
    __syncthreads();

    const float bj = bias[j];
    float acc[RPB];
    #pragma unroll
    for (int r = 0; r < RPB; ++r) acc[r] = bj;

    for (int d = 0; d < DD; d += 4) {
        const float w0 = W[(size_t)(d + 0) * DD + j];   // coalesced across j, L2-hit
        const float w1 = W[(size_t)(d + 1) * DD + j];
        const float w2 = W[(size_t)(d + 2) * DD + j];
        const float w3 = W[(size_t)(d + 3) * DD + j];
        #pragma unroll
        for (int r = 0; r < RPB; ++r) {
            const float4 xv = *(const float4*)&xs[r][d];   // LDS broadcast
            acc[r] = fmaf(xv.x, w0, fmaf(xv.y, w1, fmaf(xv.z, w2, fmaf(xv.w, w3, acc[r]))));
        }
    }

    // per-row sum of squares: wave shuffle reduce, then 4 wave-partials via LDS
    __shared__ float part[RPB][4];
    #pragma unroll
    for (int r = 0; r < RPB; ++r) {
        float s = acc[r] * acc[r];
        #pragma unroll
        for (int off = 32; off > 0; off >>= 1) s += __shfl_xor(s, off, 64);
        if (lane == 0) part[r][wid] = s;
    }
    __syncthreads();
    __shared__ float inv_s[RPB];
    if (j < RPB) {
        const float s = part[j][0] + part[j][1] + part[j][2] + part[j][3];
        inv_s[j] = 1.0f / fmaxf(sqrtf(s), EPSF);
    }
    __syncthreads();

    #pragma unroll
    for (int r = 0; r < RPB; ++r) {
        const int row = row0 + r;
        float* y = (row < BB * CC) ? (c_out + (size_t)row * DD)
                                   : (h_out + (size_t)(row - BB * CC) * DD);
        y[j] = acc[r] * inv_s[r];
    }
}

// ---------------- Kernel 2: attn + wave-parallel top-K per (b,c).
__global__ void attn_topk_kernel(const float* __restrict__ c_n,   // [B*C, D]
                                 const float* __restrict__ h_n,   // [B*H, D]
                                 float2* __restrict__ wvidx)      // [B*C*K]
{
    const int bc   = blockIdx.x;     // 0..159
    const int b    = bc / CC;
    const int tid  = threadIdx.x;    // 0..255
    const int wid  = tid >> 6;
    const int lane = tid & 63;

    __shared__ float cs[DD];
    __shared__ float attn_s[64];
    cs[tid] = c_n[(size_t)bc * DD + tid];
    if (tid < 64) attn_s[tid] = -INFINITY;
    __syncthreads();

    for (int h = wid; h < HH; h += 4) {
        const float* hr = h_n + (size_t)(b * HH + h) * DD;
        float p = 0.f;
        #pragma unroll
        for (int i = 0; i < 4; ++i) p += cs[lane + i * 64] * hr[lane + i * 64];
        #pragma unroll
        for (int off = 32; off > 0; off >>= 1) p += __shfl_down(p, off, 64);
        if (lane == 0) attn_s[h] = p;
    }
    __syncthreads();

    // wave 0: 10 rounds of butterfly argmax (tie -> lowest index, = lax.top_k)
    if (wid == 0) {
        float v   = attn_s[lane];    // lanes 50..63 hold -inf
        int   myi = lane;
        for (int k = 0; k < KK; ++k) {
            float bv = v;
            int   bi = myi;
            #pragma unroll
            for (int off = 32; off > 0; off >>= 1) {
                const float ov = __shfl_xor(bv, off, 64);
                const int   oi = __shfl_xor(bi, off, 64);
                if (ov > bv || (ov == bv && oi < bi)) { bv = ov; bi = oi; }
            }
            if (lane == 0)
                wvidx[bc * KK + k] = make_float2((bv < THRESH) ? 0.0f : bv,
                                                 __int_as_float(bi));
            if (myi == bi) v = -INFINITY;   // remove winner
        }
    }
}

// ---------------- Kernel 3: sparse overwrite of NONZERO rows only (measured ~3-5 us).
__global__ __launch_bounds__(256)
void sparse_gather_kernel(const float* __restrict__ emb,     // [B,H, INNER]
                          const float2* __restrict__ wvidx,  // [NBCK]
                          float* __restrict__ out)
{
    const int g     = blockIdx.x;    // 0 .. NBCK*CHUNKS-1
    const int blk   = g >> 2;        // (b,c,k)
    const int chunk = g & 3;

    const float2 wi = wvidx[blk];    // one 8B load
    if (wi.x == 0.0f) return;        // dead rows already zeroed by zero_fill_kernel

    const int b  = blk / (CC * KK);
    const int hi = __float_as_int(wi.y);

    const f32x4* src = (const f32x4*)(emb + (size_t)(b * HH + hi) * INNER)
                       + chunk * PERCH + threadIdx.x;
    f32x4* dst = (f32x4*)(out + (size_t)blk * INNER) + chunk * PERCH + threadIdx.x;

    #pragma unroll
    for (int u = 0; u < PERCH / 256; ++u)
        __builtin_nontemporal_store(src[256 * u] * wi.x, dst + 256 * u);
}

extern "C" void kernel_launch(void* const* d_in, const int* in_sizes, int n_in,
                              void* d_out, int out_size, void* d_ws, size_t ws_size,
                              hipStream_t stream) {
    const float* cdd  = (const float*)d_in[0];   // [B,C,D]
    const float* his  = (const float*)d_in[1];   // [B,H,D]
    const float* emb  = (const float*)d_in[2];   // [B,H,L,LEV,D]
    const float* W    = (const float*)d_in[3];   // [D,D]
    const float* bias = (const float*)d_in[4];   // [D]
    float* out = (float*)d_out;

    // workspace layout
    char* ws = (char*)d_ws;
    float*  c_n   = (float*)ws;                              // B*C*D floats = 163840 B
    float*  h_n   = (float*)(ws + 163840);                   // B*H*D floats = 1638400 B
    float2* wvidx = (float2*)(ws + 163840 + 1638400);        // NBCK float2  = 12800 B

    // 1) zero the whole output with OUR fill kernel (driver memset node measured 1.7 TB/s)
    zero_fill_kernel<<<NFILL, 256, 0, stream>>>(out);

    // 2-3) front-end (measured ~4-6 us total)
    proj_norm_kernel<<<NPROJ, DD, 0, stream>>>(cdd, his, W, bias, c_n, h_n);
    attn_topk_kernel<<<BB * CC, DD, 0, stream>>>(c_n, h_n, wvidx);

    // 4) overwrite only nonzero rows (measured ~3-5 us)
    sparse_gather_kernel<<<NBCK * CHUNKS, 256, 0, stream>>>(emb, wvidx, out);
}

// Round 10
// 77.753 us; speedup vs baseline: 1.2736x; 1.2736x over previous
//
#include <hip/hip_runtime.h>
#include <math.h>

#define BB 32
#define CC 5
#define HH 50
#define LL 32
#define LEV 3
#define DD 256
#define KK 10
#define THRESH 0.1f
#define EPSF 1e-12f
#define RPB 8                      // rows per block in proj kernel
#define NPROJ ((BB * CC + BB * HH) / RPB)   // 220 blocks
#define INNER (LL * LEV * DD)      // 24576 floats per (b,c,k)
#define INNER4 (INNER / 4)         // 6144 float4 per (b,c,k)
#define NBCK (BB * CC * KK)        // 1600 output rows
#define CHUNKS 4
#define PERCH (INNER4 / CHUNKS)    // 1536 float4 per chunk (6 per thread @256)

typedef float f32x4 __attribute__((ext_vector_type(4)));

// System-scope non-temporal streaming store: bypass/no-allocate L2 and MALL.
// (sc0 sc1 = system scope, nt = non-temporal -- gfx950 MUBUF/FLAT cache flags)
__device__ __forceinline__ void store_stream(f32x4 v, f32x4* p) {
    asm volatile("global_store_dwordx4 %0, %1, off sc0 sc1 nt"
                 :: "v"(p), "v"(v) : "memory");
}

// ---------------- Kernel 1: y = l2norm(x @ W + b), 8 rows per block.
__global__ void proj_norm_kernel(const float* __restrict__ cdd,
                                 const float* __restrict__ his,
                                 const float* __restrict__ W,
                                 const float* __restrict__ bias,
                                 float* __restrict__ c_out,   // [B*C, D]
                                 float* __restrict__ h_out)   // [B*H, D]
{
    const int row0 = blockIdx.x * RPB;
    const int j    = threadIdx.x;     // 0..255
    const int wid  = j >> 6;
    const int lane = j & 63;

    __shared__ float xs[RPB][DD];
    #pragma unroll
    for (int r = 0; r < RPB; ++r) {
        const int row = row0 + r;
        const float* x = (row < BB * CC) ? (cdd + (size_t)row * DD)
                                         : (his + (size_t)(row - BB * CC) * DD);
        xs[r][j] = x[j];
    }
    __syncthreads();

    const float bj = bias[j];
    float acc[RPB];
    #pragma unroll
    for (int r = 0; r < RPB; ++r) acc[r] = bj;

    for (int d = 0; d < DD; d += 4) {
        const float w0 = W[(size_t)(d + 0) * DD + j];   // coalesced across j, L2-hit
        const float w1 = W[(size_t)(d + 1) * DD + j];
        const float w2 = W[(size_t)(d + 2) * DD + j];
        const float w3 = W[(size_t)(d + 3) * DD + j];
        #pragma unroll
        for (int r = 0; r < RPB; ++r) {
            const float4 xv = *(const float4*)&xs[r][d];   // LDS broadcast
            acc[r] = fmaf(xv.x, w0, fmaf(xv.y, w1, fmaf(xv.z, w2, fmaf(xv.w, w3, acc[r]))));
        }
    }

    // per-row sum of squares: wave shuffle reduce, then 4 wave-partials via LDS
    __shared__ float part[RPB][4];
    #pragma unroll
    for (int r = 0; r < RPB; ++r) {
        float s = acc[r] * acc[r];
        #pragma unroll
        for (int off = 32; off > 0; off >>= 1) s += __shfl_xor(s, off, 64);
        if (lane == 0) part[r][wid] = s;
    }
    __syncthreads();
    __shared__ float inv_s[RPB];
    if (j < RPB) {
        const float s = part[j][0] + part[j][1] + part[j][2] + part[j][3];
        inv_s[j] = 1.0f / fmaxf(sqrtf(s), EPSF);
    }
    __syncthreads();

    #pragma unroll
    for (int r = 0; r < RPB; ++r) {
        const int row = row0 + r;
        float* y = (row < BB * CC) ? (c_out + (size_t)row * DD)
                                   : (h_out + (size_t)(row - BB * CC) * DD);
        y[j] = acc[r] * inv_s[r];
    }
}

// ---------------- Kernel 2: attn + wave-parallel top-K per (b,c).
__global__ void attn_topk_kernel(const float* __restrict__ c_n,   // [B*C, D]
                                 const float* __restrict__ h_n,   // [B*H, D]
                                 float2* __restrict__ wvidx)      // [B*C*K]
{
    const int bc   = blockIdx.x;     // 0..159
    const int b    = bc / CC;
    const int tid  = threadIdx.x;    // 0..255
    const int wid  = tid >> 6;
    const int lane = tid & 63;

    __shared__ float cs[DD];
    __shared__ float attn_s[64];
    cs[tid] = c_n[(size_t)bc * DD + tid];
    if (tid < 64) attn_s[tid] = -INFINITY;
    __syncthreads();

    for (int h = wid; h < HH; h += 4) {
        const float* hr = h_n + (size_t)(b * HH + h) * DD;
        float p = 0.f;
        #pragma unroll
        for (int i = 0; i < 4; ++i) p += cs[lane + i * 64] * hr[lane + i * 64];
        #pragma unroll
        for (int off = 32; off > 0; off >>= 1) p += __shfl_down(p, off, 64);
        if (lane == 0) attn_s[h] = p;
    }
    __syncthreads();

    // wave 0: 10 rounds of butterfly argmax (tie -> lowest index, = lax.top_k)
    if (wid == 0) {
        float v   = attn_s[lane];    // lanes 50..63 hold -inf
        int   myi = lane;
        for (int k = 0; k < KK; ++k) {
            float bv = v;
            int   bi = myi;
            #pragma unroll
            for (int off = 32; off > 0; off >>= 1) {
                const float ov = __shfl_xor(bv, off, 64);
                const int   oi = __shfl_xor(bi, off, 64);
                if (ov > bv || (ov == bv && oi < bi)) { bv = ov; bi = oi; }
            }
            if (lane == 0)
                wvidx[bc * KK + k] = make_float2((bv < THRESH) ? 0.0f : bv,
                                                 __int_as_float(bi));
            if (myi == bi) v = -INFINITY;   // remove winner
        }
    }
}

// ---------------- Kernel 3: single-pass gather+scale (R3 structure),
// stores via system-scope streaming asm (sc0 sc1 nt) to bypass MALL dirty-hit path.
__global__ __launch_bounds__(256)
void gather_scale_kernel(const float* __restrict__ emb,     // [B,H, INNER]
                         const float2* __restrict__ wvidx,  // [NBCK]
                         float* __restrict__ out)
{
    const int g     = blockIdx.x;    // 0 .. NBCK*CHUNKS-1
    const int blk   = g >> 2;        // (b,c,k)
    const int chunk = g & 3;
    const int b     = blk / (CC * KK);

    const float2 wi = wvidx[blk];    // one 8B load per block
    const float  w_ = wi.x;

    f32x4* dst = (f32x4*)(out + (size_t)blk * INNER) + chunk * PERCH + threadIdx.x;

    if (w_ == 0.0f) {
        const f32x4 z = (f32x4){0.f, 0.f, 0.f, 0.f};
        #pragma unroll
        for (int u = 0; u < PERCH / 256; ++u)
            store_stream(z, dst + 256 * u);
    } else {
        const int hi = __float_as_int(wi.y);
        const f32x4* src = (const f32x4*)(emb + (size_t)(b * HH + hi) * INNER)
                           + chunk * PERCH + threadIdx.x;
        #pragma unroll
        for (int u = 0; u < PERCH / 256; ++u)
            store_stream(src[256 * u] * w_, dst + 256 * u);
    }
}

extern "C" void kernel_launch(void* const* d_in, const int* in_sizes, int n_in,
                              void* d_out, int out_size, void* d_ws, size_t ws_size,
                              hipStream_t stream) {
    const float* cdd  = (const float*)d_in[0];   // [B,C,D]
    const float* his  = (const float*)d_in[1];   // [B,H,D]
    const float* emb  = (const float*)d_in[2];   // [B,H,L,LEV,D]
    const float* W    = (const float*)d_in[3];   // [D,D]
    const float* bias = (const float*)d_in[4];   // [D]
    float* out = (float*)d_out;

    // workspace layout
    char* ws = (char*)d_ws;
    float*  c_n   = (float*)ws;                              // B*C*D floats = 163840 B
    float*  h_n   = (float*)(ws + 163840);                   // B*H*D floats = 1638400 B
    float2* wvidx = (float2*)(ws + 163840 + 1638400);        // NBCK float2  = 12800 B

    proj_norm_kernel<<<NPROJ, DD, 0, stream>>>(cdd, his, W, bias, c_n, h_n);
    attn_topk_kernel<<<BB * CC, DD, 0, stream>>>(c_n, h_n, wvidx);
    gather_scale_kernel<<<NBCK * CHUNKS, 256, 0, stream>>>(emb, wvidx, out);
}